// Round 11
// baseline (16.131 us; speedup 1.0000x reference)
//
#include <hip/hip_runtime.h>
#include <hip/hip_bf16.h>

// velocity = MLP(concat[zone_embedding, person_attrs, time_vec])
// GCN layers in the reference are dead code (outputs unused) -> skipped.
//
// Round-11: two-kernel split. Rounds 6-8 failed to HIDE the per-block
// preamble (3x syncthreads GEMV chain + 80 scattered weight-fragment
// gathers per wave, repeated 768 blocks / 3072 waves); this round DELETES
// it. Setup kernel (1 block) computes time_vec + h1_base and packs all
// MFMA weight fragments into d_ws in per-lane register order
// [reg 0..9][lane 0..63][8 bf16]; main kernel loads fragments with 10
// coalesced 1KB reads (L2-broadcast, same 10KB for every wave), has zero
// __syncthreads, and runs the verified round-5/9/10 tile loop unchanged.
// C/D map col=lane&15, row=(lane>>4)*4+reg; k=8g+j identical on A and B.

typedef __attribute__((ext_vector_type(8))) short bf16x8;
typedef __attribute__((ext_vector_type(4))) float f32x4;

#define BLK 256
#define WPB 4              // waves per block
#define H1_STRIDE 72       // bf16 elems per row: 64 + 8 pad (bank spread)
#define H2_STRIDE 40       // 32 + 8 pad

// d_ws layout: [0, 10240): frag[r][lane][j] shorts (10*64*8*2 B)
//              [10240, 10496): h1b[64] floats
#define WS_FRAG_SHORTS (10 * 64 * 8)
#define WS_H1B_OFF 10240

__device__ __forceinline__ short f2bf(float x) {
    union { __hip_bfloat16 h; short s; } u;
    u.h = __float2bfloat16(x);
    return u.s;
}

// ---------------- setup kernel: 1 block, 256 threads ----------------
__global__ __launch_bounds__(BLK) void zone_setup(
    const float* __restrict__ tp,
    const float* __restrict__ pa,
    const float* __restrict__ Wt1, const float* __restrict__ bt1,
    const float* __restrict__ Wt2, const float* __restrict__ bt2,
    const float* __restrict__ Wd1, const float* __restrict__ bd1,
    const float* __restrict__ Wd2,
    const float* __restrict__ Wd3,
    short* __restrict__ ws_frag,       // [10][64][8] bf16
    float* __restrict__ ws_h1b)        // [64]
{
    __shared__ float s_u[16];
    __shared__ float s_tv[16];

    const int tidx = threadIdx.x;
    const int wave = tidx >> 6;
    const int lane = tidx & 63;
    const int c = lane & 15;
    const int g = lane >> 4;

    // time encoder (fp32 exact)
    const float tval = tp[0];
    if (tidx < 16) s_u[tidx] = fmaxf(tval * Wt1[tidx] + bt1[tidx], 0.0f);
    __syncthreads();
    if (tidx < 16) {
        float a = bt2[tidx];
        #pragma unroll
        for (int k = 0; k < 16; k++) a = fmaf(s_u[k], Wt2[k * 16 + tidx], a);
        s_tv[tidx] = a;   // no relu on second time layer
    }
    __syncthreads();

    // h1 base: bd1 + person/time @ Wd1[32:56]
    if (tidx < 64) {
        float a = bd1[tidx];
        #pragma unroll
        for (int k = 0; k < 8; k++)
            a = fmaf(pa[k], Wd1[(32 + k) * 64 + tidx], a);
        #pragma unroll
        for (int k = 0; k < 16; k++)
            a = fmaf(s_tv[k], Wd1[(40 + k) * 64 + tidx], a);
        ws_h1b[tidx] = a;
    }

    // fragment packing: reg r, lane -> 8 bf16. Waves split the 10 regs.
    //  r 0..3 : w1f[tt=r]      = Wd1[(8g+j)*64 + 16r + c]
    //  r 4..5 : w2f[0][tt=r-4] = Wd2[(8g+j)*32 + 16(r-4) + c]
    //  r 6..7 : w2f[1][tt=r-6] = Wd2[(32+8g+j)*32 + 16(r-6) + c]
    //  r 8..9 : w3f[tt=r-8]    = Wd3[(8g+j)*32 + 16(r-8) + c]
    for (int r = wave; r < 10; r += WPB) {
        bf16x8 v;
        #pragma unroll
        for (int j = 0; j < 8; j++) {
            float w;
            if (r < 4)      w = Wd1[(8 * g + j) * 64 + 16 * r + c];
            else if (r < 6) w = Wd2[(8 * g + j) * 32 + 16 * (r - 4) + c];
            else if (r < 8) w = Wd2[(32 + 8 * g + j) * 32 + 16 * (r - 6) + c];
            else            w = Wd3[(8 * g + j) * 32 + 16 * (r - 8) + c];
            v[j] = f2bf(w);
        }
        *reinterpret_cast<bf16x8*>(ws_frag + ((size_t)r * 64 + lane) * 8) = v;
    }
}

// ---------------- main kernel: no syncthreads, no gathers ----------------
__global__ __launch_bounds__(BLK, 3) void zone_velocity_mfma(
    const float* __restrict__ emb,      // [N,32]
    const float* __restrict__ bd2,      // [32]
    const float* __restrict__ bd3,      // [32]
    const short* __restrict__ ws_frag,  // [10][64][8] bf16
    const float* __restrict__ ws_h1b,   // [64]
    float* __restrict__ out,            // [N,32]
    int N, int ntiles)
{
    __shared__ __align__(16) short s_H1[WPB][16 * H1_STRIDE];
    __shared__ __align__(16) short s_H2[WPB][16 * H2_STRIDE];

    const int tidx = threadIdx.x;
    const int wave = tidx >> 6;
    const int lane = tidx & 63;
    const int c = lane & 15;   // A-row / B-col / D-col index
    const int g = lane >> 4;   // k-group (k = 8g + j)

    // ---- fragments: 10 coalesced 1KB loads (same addrs every wave) ----
    bf16x8 w1f[4];
    bf16x8 w2f[2][2];
    bf16x8 w3f[2];
    #pragma unroll
    for (int tt = 0; tt < 4; tt++)
        w1f[tt] = *reinterpret_cast<const bf16x8*>(
            ws_frag + ((size_t)tt * 64 + lane) * 8);
    #pragma unroll
    for (int s = 0; s < 2; s++)
        #pragma unroll
        for (int tt = 0; tt < 2; tt++)
            w2f[s][tt] = *reinterpret_cast<const bf16x8*>(
                ws_frag + ((size_t)(4 + 2 * s + tt) * 64 + lane) * 8);
    #pragma unroll
    for (int tt = 0; tt < 2; tt++)
        w3f[tt] = *reinterpret_cast<const bf16x8*>(
            ws_frag + ((size_t)(8 + tt) * 64 + lane) * 8);

    // ---- per-lane biases ----
    float h1b[4];
    #pragma unroll
    for (int tt = 0; tt < 4; tt++) h1b[tt] = ws_h1b[16 * tt + c];
    float b2r[2] = { bd2[c], bd2[16 + c] };
    float b3r[2] = { bd3[c], bd3[16 + c] };

    short* H1 = s_H1[wave];
    short* H2 = s_H2[wave];

    const int wid = blockIdx.x * WPB + wave;
    const int nw  = gridDim.x * WPB;

    for (int tile = wid; tile < ntiles; tile += nw) {
        const int zb = tile * 16;

        // ---- X fragment: row = c (zone), k = 8g+j (emb channel) ----
        const int zr  = zb + c;
        const int zrc = (zr < N) ? zr : (N - 1);
        const float* ep = emb + (size_t)zrc * 32 + 8 * g;
        float4 xa = *reinterpret_cast<const float4*>(ep);
        float4 xb = *reinterpret_cast<const float4*>(ep + 4);
        bf16x8 af;
        af[0] = f2bf(xa.x); af[1] = f2bf(xa.y); af[2] = f2bf(xa.z); af[3] = f2bf(xa.w);
        af[4] = f2bf(xb.x); af[5] = f2bf(xb.y); af[6] = f2bf(xb.z); af[7] = f2bf(xb.w);

        // ---- layer 1: H1[16,64] = relu(X @ Wd1[0:32] + h1b) ----
        f32x4 acc1[4];
        #pragma unroll
        for (int tt = 0; tt < 4; tt++) {
            f32x4 ci; ci[0] = ci[1] = ci[2] = ci[3] = h1b[tt];
            acc1[tt] = __builtin_amdgcn_mfma_f32_16x16x32_bf16(af, w1f[tt], ci, 0, 0, 0);
        }
        // relu -> LDS (D map: row m = 4g+r, col n = 16tt+c)
        #pragma unroll
        for (int tt = 0; tt < 4; tt++)
            #pragma unroll
            for (int r = 0; r < 4; r++)
                H1[(4 * g + r) * H1_STRIDE + 16 * tt + c] =
                    f2bf(fmaxf(acc1[tt][r], 0.0f));

        __builtin_amdgcn_wave_barrier();
        asm volatile("s_waitcnt lgkmcnt(0)" ::: "memory");
        __builtin_amdgcn_sched_barrier(0);

        // ---- layer 2: H2[16,32] = relu(H1 @ Wd2 + bd2), K=64 in 2 steps ----
        f32x4 acc2[2];
        #pragma unroll
        for (int tt = 0; tt < 2; tt++) {
            f32x4 ci; ci[0] = ci[1] = ci[2] = ci[3] = b2r[tt];
            acc2[tt] = ci;
        }
        #pragma unroll
        for (int s = 0; s < 2; s++) {
            bf16x8 a2 = *reinterpret_cast<const bf16x8*>(
                H1 + c * H1_STRIDE + 32 * s + 8 * g);   // row=c, k=32s+8g+j
            #pragma unroll
            for (int tt = 0; tt < 2; tt++)
                acc2[tt] = __builtin_amdgcn_mfma_f32_16x16x32_bf16(
                    a2, w2f[s][tt], acc2[tt], 0, 0, 0);
        }
        #pragma unroll
        for (int tt = 0; tt < 2; tt++)
            #pragma unroll
            for (int r = 0; r < 4; r++)
                H2[(4 * g + r) * H2_STRIDE + 16 * tt + c] =
                    f2bf(fmaxf(acc2[tt][r], 0.0f));

        __builtin_amdgcn_wave_barrier();
        asm volatile("s_waitcnt lgkmcnt(0)" ::: "memory");
        __builtin_amdgcn_sched_barrier(0);

        // ---- layer 3: O[16,32] = H2 @ Wd3 + bd3 ----
        bf16x8 a3 = *reinterpret_cast<const bf16x8*>(H2 + c * H2_STRIDE + 8 * g);
        f32x4 acc3[2];
        #pragma unroll
        for (int tt = 0; tt < 2; tt++) {
            f32x4 ci; ci[0] = ci[1] = ci[2] = ci[3] = b3r[tt];
            acc3[tt] = __builtin_amdgcn_mfma_f32_16x16x32_bf16(a3, w3f[tt], ci, 0, 0, 0);
        }

        // ---- store: zone = zb + 4g + r, channel = 16tt + c ----
        #pragma unroll
        for (int r = 0; r < 4; r++) {
            const int zo = zb + 4 * g + r;
            if (zo < N) {
                float* op = out + (size_t)zo * 32;
                op[c]      = acc3[0][r];
                op[16 + c] = acc3[1][r];
            }
        }
    }
}

extern "C" void kernel_launch(void* const* d_in, const int* in_sizes, int n_in,
                              void* d_out, int out_size, void* d_ws, size_t ws_size,
                              hipStream_t stream) {
    // setup_inputs() order:
    //  0 t, 1 zone_embedding, 2 zone_features, 3 person_attrs, 4 edge_index,
    //  5 W1, 6 b1, 7 W2, 8 b2, 9 Wt1, 10 bt1, 11 Wt2, 12 bt2,
    // 13 Wd1, 14 bd1, 15 Wd2, 16 bd2, 17 Wd3, 18 bd3
    const float* t   = (const float*)d_in[0];
    const float* emb = (const float*)d_in[1];
    const float* pa  = (const float*)d_in[3];
    const float* Wt1 = (const float*)d_in[9];
    const float* bt1 = (const float*)d_in[10];
    const float* Wt2 = (const float*)d_in[11];
    const float* bt2 = (const float*)d_in[12];
    const float* Wd1 = (const float*)d_in[13];
    const float* bd1 = (const float*)d_in[14];
    const float* Wd2 = (const float*)d_in[15];
    const float* bd2 = (const float*)d_in[16];
    const float* Wd3 = (const float*)d_in[17];
    const float* bd3 = (const float*)d_in[18];

    const int N = in_sizes[1] / 32;          // 100000
    const int ntiles = (N + 15) / 16;        // 6250
    float* out = (float*)d_out;

    short* ws_frag = (short*)d_ws;
    float* ws_h1b  = (float*)((char*)d_ws + WS_H1B_OFF);

    // kernel A: one block packs fragments + h1 base into d_ws
    zone_setup<<<1, BLK, 0, stream>>>(
        t, pa, Wt1, bt1, Wt2, bt2, Wd1, bd1, Wd2, Wd3, ws_frag, ws_h1b);

    // kernel B: 768 = 256 CUs x 3 blocks/CU (LB(256,3)): zero dispatch tail.
    zone_velocity_mfma<<<768, BLK, 0, stream>>>(
        emb, bd2, bd3, ws_frag, ws_h1b, out, N, ntiles);
}

// Round 12
// 13.073 us; speedup vs baseline: 1.2340x; 1.2340x over previous
//
#include <hip/hip_runtime.h>
#include <hip/hip_bf16.h>

// velocity = MLP(concat[zone_embedding, person_attrs, time_vec])
// GCN layers in the reference are dead code (outputs unused) -> skipped.
//
// Round-12: REVERT to the round-10 kernel (best measured: 12.98us).
// Round-11's two-kernel split measured 16.13us (outside +1.7us noise):
// the serial setup dispatch (~+3us) swamped the preamble saving. Session
// ledger: R5 15.56 / R9 A/A 13.90 / R10 (grid 768) 12.98 / six structural
// probes all >= noise-band. Model: ~3us memory floor + ~10us fixed
// dispatch/latency overhead => flat landscape at ~13us. This is the
// terminal kernel; expect 12-15.5us.
//
// Per wave: 16-zone tile, 10 x mfma_f32_16x16x32_bf16 (4 + 2x2 + 2).
// Inter-layer re-fragmentation via per-wave LDS tiles (bf16, padded strides
// 72/40 bf16 -> <=2-way bank aliasing = free). Only HW layout assumed is the
// verified C/D map: col=lane&15, row=(lane>>4)*4+reg. A/B k-indexing k=8g+j
// is applied identically to both operands -> correct under any internal
// slot->k routing (k-sum is reindex-invariant). Bias/person/time folded into
// fp32 C-init (exact). Grid = 768 = 256 CU x 3 blocks/CU (LB(256,3)):
// zero dispatch tail; grid-stride loop gives 106 waves a 3rd tile.

typedef __attribute__((ext_vector_type(8))) short bf16x8;
typedef __attribute__((ext_vector_type(4))) float f32x4;

#define BLK 256
#define WPB 4              // waves per block
#define H1_STRIDE 72       // bf16 elems per row: 64 + 8 pad (bank spread)
#define H2_STRIDE 40       // 32 + 8 pad

__device__ __forceinline__ short f2bf(float x) {
    union { __hip_bfloat16 h; short s; } u;
    u.h = __float2bfloat16(x);
    return u.s;
}

__global__ __launch_bounds__(BLK, 3) void zone_velocity_mfma(
    const float* __restrict__ tp,
    const float* __restrict__ emb,      // [N,32]
    const float* __restrict__ pa,       // [8]
    const float* __restrict__ Wt1, const float* __restrict__ bt1,
    const float* __restrict__ Wt2, const float* __restrict__ bt2,
    const float* __restrict__ Wd1, const float* __restrict__ bd1,  // [56,64],[64]
    const float* __restrict__ Wd2, const float* __restrict__ bd2,  // [64,32],[32]
    const float* __restrict__ Wd3, const float* __restrict__ bd3,  // [32,32],[32]
    float* __restrict__ out,            // [N,32]
    int N, int ntiles)
{
    __shared__ float s_u[16];
    __shared__ float s_tv[16];
    __shared__ float s_h1b[64];
    __shared__ __align__(16) short s_H1[WPB][16 * H1_STRIDE];
    __shared__ __align__(16) short s_H2[WPB][16 * H2_STRIDE];

    const int tidx = threadIdx.x;
    const int wave = tidx >> 6;
    const int lane = tidx & 63;
    const int c = lane & 15;   // A-row / B-col / D-col index
    const int g = lane >> 4;   // k-group (k = 8g + j)

    // ---- time encoder (fp32 exact) ----
    const float tval = tp[0];
    if (tidx < 16) s_u[tidx] = fmaxf(tval * Wt1[tidx] + bt1[tidx], 0.0f);
    __syncthreads();
    if (tidx < 16) {
        float a = bt2[tidx];
        #pragma unroll
        for (int k = 0; k < 16; k++) a = fmaf(s_u[k], Wt2[k * 16 + tidx], a);
        s_tv[tidx] = a;  // no relu on second time layer
    }
    __syncthreads();

    // ---- h1 base: bd1 + person/time @ Wd1[32:56] (zone-uniform, fp32) ----
    if (tidx < 64) {
        float a = bd1[tidx];
        #pragma unroll
        for (int k = 0; k < 8; k++)
            a = fmaf(pa[k], Wd1[(32 + k) * 64 + tidx], a);
        #pragma unroll
        for (int k = 0; k < 16; k++)
            a = fmaf(s_tv[k], Wd1[(40 + k) * 64 + tidx], a);
        s_h1b[tidx] = a;
    }
    __syncthreads();

    // ---- per-lane biases ----
    float h1b[4];
    #pragma unroll
    for (int tt = 0; tt < 4; tt++) h1b[tt] = s_h1b[16 * tt + c];
    float b2r[2] = { bd2[c], bd2[16 + c] };
    float b3r[2] = { bd3[c], bd3[16 + c] };

    // ---- weight fragments (loaded once; k = 8g + j on BOTH operands) ----
    bf16x8 w1f[4];        // Wd1[0:32] -> 4 n-tiles
    bf16x8 w2f[2][2];     // Wd2: 2 k-steps x 2 n-tiles
    bf16x8 w3f[2];        // Wd3: 2 n-tiles
    #pragma unroll
    for (int tt = 0; tt < 4; tt++)
        #pragma unroll
        for (int j = 0; j < 8; j++)
            w1f[tt][j] = f2bf(Wd1[(8 * g + j) * 64 + 16 * tt + c]);
    #pragma unroll
    for (int s = 0; s < 2; s++)
        #pragma unroll
        for (int tt = 0; tt < 2; tt++)
            #pragma unroll
            for (int j = 0; j < 8; j++)
                w2f[s][tt][j] = f2bf(Wd2[(32 * s + 8 * g + j) * 32 + 16 * tt + c]);
    #pragma unroll
    for (int tt = 0; tt < 2; tt++)
        #pragma unroll
        for (int j = 0; j < 8; j++)
            w3f[tt][j] = f2bf(Wd3[(8 * g + j) * 32 + 16 * tt + c]);

    short* H1 = s_H1[wave];
    short* H2 = s_H2[wave];

    const int wid = blockIdx.x * WPB + wave;
    const int nw  = gridDim.x * WPB;

    for (int tile = wid; tile < ntiles; tile += nw) {
        const int zb = tile * 16;

        // ---- X fragment: row = c (zone), k = 8g+j (emb channel) ----
        const int zr  = zb + c;
        const int zrc = (zr < N) ? zr : (N - 1);
        const float* ep = emb + (size_t)zrc * 32 + 8 * g;
        float4 xa = *reinterpret_cast<const float4*>(ep);
        float4 xb = *reinterpret_cast<const float4*>(ep + 4);
        bf16x8 af;
        af[0] = f2bf(xa.x); af[1] = f2bf(xa.y); af[2] = f2bf(xa.z); af[3] = f2bf(xa.w);
        af[4] = f2bf(xb.x); af[5] = f2bf(xb.y); af[6] = f2bf(xb.z); af[7] = f2bf(xb.w);

        // ---- layer 1: H1[16,64] = relu(X @ Wd1[0:32] + h1b) ----
        f32x4 acc1[4];
        #pragma unroll
        for (int tt = 0; tt < 4; tt++) {
            f32x4 ci; ci[0] = ci[1] = ci[2] = ci[3] = h1b[tt];
            acc1[tt] = __builtin_amdgcn_mfma_f32_16x16x32_bf16(af, w1f[tt], ci, 0, 0, 0);
        }
        // relu -> LDS (D map: row m = 4g+r, col n = 16tt+c)
        #pragma unroll
        for (int tt = 0; tt < 4; tt++)
            #pragma unroll
            for (int r = 0; r < 4; r++)
                H1[(4 * g + r) * H1_STRIDE + 16 * tt + c] =
                    f2bf(fmaxf(acc1[tt][r], 0.0f));

        __builtin_amdgcn_wave_barrier();
        asm volatile("s_waitcnt lgkmcnt(0)" ::: "memory");
        __builtin_amdgcn_sched_barrier(0);

        // ---- layer 2: H2[16,32] = relu(H1 @ Wd2 + bd2), K=64 in 2 steps ----
        f32x4 acc2[2];
        #pragma unroll
        for (int tt = 0; tt < 2; tt++) {
            f32x4 ci; ci[0] = ci[1] = ci[2] = ci[3] = b2r[tt];
            acc2[tt] = ci;
        }
        #pragma unroll
        for (int s = 0; s < 2; s++) {
            bf16x8 a2 = *reinterpret_cast<const bf16x8*>(
                H1 + c * H1_STRIDE + 32 * s + 8 * g);   // row=c, k=32s+8g+j
            #pragma unroll
            for (int tt = 0; tt < 2; tt++)
                acc2[tt] = __builtin_amdgcn_mfma_f32_16x16x32_bf16(
                    a2, w2f[s][tt], acc2[tt], 0, 0, 0);
        }
        #pragma unroll
        for (int tt = 0; tt < 2; tt++)
            #pragma unroll
            for (int r = 0; r < 4; r++)
                H2[(4 * g + r) * H2_STRIDE + 16 * tt + c] =
                    f2bf(fmaxf(acc2[tt][r], 0.0f));

        __builtin_amdgcn_wave_barrier();
        asm volatile("s_waitcnt lgkmcnt(0)" ::: "memory");
        __builtin_amdgcn_sched_barrier(0);

        // ---- layer 3: O[16,32] = H2 @ Wd3 + bd3 ----
        bf16x8 a3 = *reinterpret_cast<const bf16x8*>(H2 + c * H2_STRIDE + 8 * g);
        f32x4 acc3[2];
        #pragma unroll
        for (int tt = 0; tt < 2; tt++) {
            f32x4 ci; ci[0] = ci[1] = ci[2] = ci[3] = b3r[tt];
            acc3[tt] = __builtin_amdgcn_mfma_f32_16x16x32_bf16(a3, w3f[tt], ci, 0, 0, 0);
        }

        // ---- store: zone = zb + 4g + r, channel = 16tt + c ----
        #pragma unroll
        for (int r = 0; r < 4; r++) {
            const int zo = zb + 4 * g + r;
            if (zo < N) {
                float* op = out + (size_t)zo * 32;
                op[c]      = acc3[0][r];
                op[16 + c] = acc3[1][r];
            }
        }
    }
}

extern "C" void kernel_launch(void* const* d_in, const int* in_sizes, int n_in,
                              void* d_out, int out_size, void* d_ws, size_t ws_size,
                              hipStream_t stream) {
    // setup_inputs() order:
    //  0 t, 1 zone_embedding, 2 zone_features, 3 person_attrs, 4 edge_index,
    //  5 W1, 6 b1, 7 W2, 8 b2, 9 Wt1, 10 bt1, 11 Wt2, 12 bt2,
    // 13 Wd1, 14 bd1, 15 Wd2, 16 bd2, 17 Wd3, 18 bd3
    const float* t   = (const float*)d_in[0];
    const float* emb = (const float*)d_in[1];
    const float* pa  = (const float*)d_in[3];
    const float* Wt1 = (const float*)d_in[9];
    const float* bt1 = (const float*)d_in[10];
    const float* Wt2 = (const float*)d_in[11];
    const float* bt2 = (const float*)d_in[12];
    const float* Wd1 = (const float*)d_in[13];
    const float* bd1 = (const float*)d_in[14];
    const float* Wd2 = (const float*)d_in[15];
    const float* bd2 = (const float*)d_in[16];
    const float* Wd3 = (const float*)d_in[17];
    const float* bd3 = (const float*)d_in[18];

    const int N = in_sizes[1] / 32;          // 100000
    const int ntiles = (N + 15) / 16;        // 6250
    float* out = (float*)d_out;

    // grid = 768 = 256 CUs x 3 blocks/CU (LB(256,3)): zero dispatch tail.
    // 3072 waves; all do 2 tiles, 106 waves take a 3rd (grid-stride loop).
    const int blocks = 768;
    zone_velocity_mfma<<<blocks, BLK, 0, stream>>>(
        t, emb, pa, Wt1, bt1, Wt2, bt2,
        Wd1, bd1, Wd2, bd2, Wd3, bd3, out, N, ntiles);
}